// Round 6
// baseline (36.009 us; speedup 1.0000x reference)
//
#include <hip/hip_runtime.h>

#define HW 9216
#define W 96
#define H 96
#define NC 256
#define NT 49
#define NPAIR 25
#define EPSV 1e-5f

#define TS 16
#define HSZ 22
#define CC 8
#define NZ 32

typedef _Float16 half8 __attribute__((ext_vector_type(8)));
typedef _Float16 half2v __attribute__((ext_vector_type(2)));

// ---- pack kernel -----------------------------------------------------------
// blockIdx.y < 8 : pack x fp32 (c-major) -> xpack[z][p][8ch] fp16 (16B units)
// blockIdx.y == 8: normalize weights, store half2-packed nwh[pair][p]
__global__ __launch_bounds__(256) void pack_kernel(const float* __restrict__ x,
                                                   const float* __restrict__ w,
                                                   _Float16* __restrict__ xpack,
                                                   half2v* __restrict__ nwh) {
    if (blockIdx.y < 8) {
        const int g = blockIdx.y * 4 + (threadIdx.x >> 6);   // chgroup 0..31
        const int px = blockIdx.x * 64 + (threadIdx.x & 63); // pixel
        const float* __restrict__ sp = x + (size_t)(g * 8) * HW + px;
        half8 h;
#pragma unroll
        for (int c = 0; c < 8; ++c) h[c] = (_Float16)sp[c * HW];
        *(half8*)(xpack + ((size_t)g * HW + px) * 8) = h;
    } else {
        if (blockIdx.x >= 36) return;
        const int p = blockIdx.x * 256 + threadIdx.x;
        float wv[NT];
        float s = 0.f;
#pragma unroll
        for (int t = 0; t < NT; ++t) { wv[t] = w[t * HW + p]; s += wv[t]; }
        const float inv = 1.f / (s + EPSV);
#pragma unroll
        for (int i = 0; i < NPAIR; ++i) {
            half2v h;
            h[0] = (_Float16)(wv[2 * i] * inv);
            h[1] = (2 * i + 1 < NT) ? (_Float16)(wv[2 * i + 1] * inv) : (_Float16)0.f;
            nwh[i * HW + p] = h;
        }
    }
}

// ---- message-passing step (packed fp16 in/weights, fp32 accumulate) --------
// FUSE=0: out = xnext[z][p][8] fp16.  FUSE=1: out = partial[z*3+o][p] fp32.
template <int FUSE_CONV>
__global__ __launch_bounds__(256) void step_kernel(const _Float16* __restrict__ xin,
                                                   const half2v* __restrict__ nwh,
                                                   const float* __restrict__ cw,
                                                   void* __restrict__ yout) {
    __shared__ half8 xs[HSZ][HSZ];  // 7744 B
    const int tx = threadIdx.x & 15;
    const int ty = threadIdx.x >> 4;
    const int bx = blockIdx.x * TS;
    const int by = blockIdx.y * TS;
    const int px = bx + tx;
    const int py = by + ty;
    const int p = py * W + px;
    const int z = blockIdx.z;

    // 25 packed weight dwords (normalized, fp16 pairs)
    half2v wu[NPAIR];
#pragma unroll
    for (int i = 0; i < NPAIR; ++i) wu[i] = nwh[i * HW + p];

    // stage 22x22 halo of 8 packed channels (zero-padded)
    const _Float16* __restrict__ xz = xin + (size_t)z * HW * 8;
#pragma unroll
    for (int it = 0; it < 2; ++it) {
        const int i = threadIdx.x + it * 256;
        if (i < HSZ * HSZ) {
            const int hy = i / HSZ;
            const int hx = i - hy * HSZ;
            const int gy = by - 3 + hy;
            const int gx = bx - 3 + hx;
            half8 v;
#pragma unroll
            for (int c = 0; c < 8; ++c) v[c] = (_Float16)0.f;
            if ((unsigned)gy < (unsigned)H && (unsigned)gx < (unsigned)W)
                v = *(const half8*)(xz + (size_t)(gy * W + gx) * 8);
            xs[hy][hx] = v;
        }
    }
    __syncthreads();

    float acc[8];
#pragma unroll
    for (int k = 0; k < 8; ++k) acc[k] = 0.f;

#pragma unroll
    for (int i = 0; i < 7; ++i) {
#pragma unroll
        for (int j = 0; j < 7; ++j) {
            const int t = i * 7 + j;
            const float wf = (float)wu[t >> 1][t & 1];
            const half8 v = xs[ty + i][tx + j];
#pragma unroll
            for (int k = 0; k < 8; ++k)
                acc[k] = fmaf(wf, (float)v[k], acc[k]);
        }
    }

    if (FUSE_CONV) {
        float o0 = 0.f, o1 = 0.f, o2 = 0.f;
        const int cbase = z * CC;
#pragma unroll
        for (int k = 0; k < 8; ++k) {
            const int c = cbase + k;
            o0 = fmaf(acc[k], cw[c], o0);
            o1 = fmaf(acc[k], cw[NC + c], o1);
            o2 = fmaf(acc[k], cw[2 * NC + c], o2);
        }
        float* __restrict__ part = (float*)yout;
        part[(z * 3 + 0) * HW + p] = o0;
        part[(z * 3 + 1) * HW + p] = o1;
        part[(z * 3 + 2) * HW + p] = o2;
    } else {
        half8 h;
#pragma unroll
        for (int k = 0; k < 8; ++k) h[k] = (_Float16)acc[k];
        _Float16* __restrict__ yo = (_Float16*)yout;
        *(half8*)(yo + ((size_t)z * HW + p) * 8) = h;
    }
}

// ---- fused z-reduce + bias + bilinear x4 upsample --------------------------
#define OUTS 384
#define SRCP 10
__global__ __launch_bounds__(256) void upsample_kernel(const float* __restrict__ partial,
                                                       const float* __restrict__ cb,
                                                       float* __restrict__ dst) {
    __shared__ float cvs[3][SRCP][SRCP];
    const int X = blockIdx.x * 32;
    const int Y = blockIdx.y * 32;
    const int x0s = X >> 2;
    const int y0s = Y >> 2;

    for (int e = threadIdx.x; e < 3 * SRCP * SRCP; e += 256) {
        int ch = e / (SRCP * SRCP);
        int r = e - ch * (SRCP * SRCP);
        int sy = r / SRCP;
        int sx = r - sy * SRCP;
        int gy = min(max(y0s - 1 + sy, 0), H - 1);
        int gx = min(max(x0s - 1 + sx, 0), W - 1);
        const int p = gy * W + gx;
        float sum = cb[ch];
#pragma unroll
        for (int z = 0; z < NZ; ++z) sum += partial[(z * 3 + ch) * HW + p];
        cvs[ch][sy][sx] = sum;
    }
    __syncthreads();

    const int xl = threadIdx.x & 31;
    const int yl0 = threadIdx.x >> 5;
    const int xo = X + xl;
    const float sxf = xo * 0.25f - 0.375f;
    const float fxf = floorf(sxf);
    const int jx = (int)fxf - (x0s - 1);
    const float fx = sxf - fxf;

#pragma unroll
    for (int k = 0; k < 4; ++k) {
        const int yo = Y + yl0 + 8 * k;
        const float syf = yo * 0.25f - 0.375f;
        const float fyf = floorf(syf);
        const int jy = (int)fyf - (y0s - 1);
        const float fy = syf - fyf;
#pragma unroll
        for (int ch = 0; ch < 3; ++ch) {
            const float v00 = cvs[ch][jy][jx], v01 = cvs[ch][jy][jx + 1];
            const float v10 = cvs[ch][jy + 1][jx], v11 = cvs[ch][jy + 1][jx + 1];
            const float v0 = v00 + (v01 - v00) * fx;
            const float v1 = v10 + (v11 - v10) * fx;
            dst[ch * OUTS * OUTS + yo * OUTS + xo] = v0 + (v1 - v0) * fy;
        }
    }
}

extern "C" void kernel_launch(void* const* d_in, const int* in_sizes, int n_in,
                              void* d_out, int out_size, void* d_ws, size_t ws_size,
                              hipStream_t stream) {
    const float* input  = (const float*)d_in[0];   // (1,256,96,96)
    const float* weight = (const float*)d_in[1];   // (1,49,9216)
    const float* conv_w = (const float*)d_in[2];   // (3,256)
    const float* conv_b = (const float*)d_in[3];   // (3,)
    float* out = (float*)d_out;                    // (1,3,384,384)

    char* ws = (char*)d_ws;
    _Float16* xpack = (_Float16*)ws;                         // 32*9216*8*2 = 4.72 MB
    _Float16* x1h   = xpack + (size_t)NZ * HW * 8;           // 4.72 MB
    half2v*   nwh   = (half2v*)(x1h + (size_t)NZ * HW * 8);  // 25*9216*4 = 0.92 MB
    float*  partial = (float*)((char*)nwh + (size_t)NPAIR * HW * 4);  // 32*3*9216*4

    dim3 gp(144, 9);
    pack_kernel<<<gp, 256, 0, stream>>>(input, weight, xpack, nwh);

    dim3 g(W / TS, H / TS, NZ);               // (6,6,32)
    step_kernel<0><<<g, 256, 0, stream>>>(xpack, nwh, nullptr, (void*)x1h);
    step_kernel<1><<<g, 256, 0, stream>>>(x1h, nwh, conv_w, (void*)partial);

    dim3 gu(OUTS / 32, OUTS / 32);            // (12,12)
    upsample_kernel<<<gu, 256, 0, stream>>>(partial, conv_b, out);
}

// Round 7
// 34.748 us; speedup vs baseline: 1.0363x; 1.0363x over previous
//
#include <hip/hip_runtime.h>

#define HW 9216
#define W 96
#define H 96
#define NC 256
#define NT 49
#define NPAIR 25
#define EPSV 1e-5f

#define TS 16
#define HSZ 22
#define CC 8
#define NZ 32

typedef _Float16 half8 __attribute__((ext_vector_type(8)));
typedef _Float16 half2v __attribute__((ext_vector_type(2)));

// ---- step1: fused pack + normalize + message passing -----------------------
// Reads fp32 x (c-major strided), normalizes weights in fp32 regs, writes
// packed-fp16 x1h[z][p][8]; z==0 blocks also emit packed nwh for step2.
__global__ __launch_bounds__(256) void step1_kernel(const float* __restrict__ x,
                                                    const float* __restrict__ w,
                                                    _Float16* __restrict__ x1h,
                                                    half2v* __restrict__ nwh) {
    __shared__ half8 xs[HSZ][HSZ];  // 7744 B
    const int tx = threadIdx.x & 15;
    const int ty = threadIdx.x >> 4;
    const int bx = blockIdx.x * TS;
    const int by = blockIdx.y * TS;
    const int px = bx + tx;
    const int py = by + ty;
    const int p = py * W + px;
    const int z = blockIdx.z;

    // ---- issue halo loads FIRST (latency hides under weight normalize) ----
    const float* __restrict__ xb = x + (size_t)z * CC * HW;
    float hv[2][8];
    int hidx[2];
#pragma unroll
    for (int it = 0; it < 2; ++it) {
        const int i = threadIdx.x + it * 256;
        hidx[it] = i;
#pragma unroll
        for (int c = 0; c < 8; ++c) hv[it][c] = 0.f;
        if (i < HSZ * HSZ) {
            const int hy = i / HSZ;
            const int hx = i - hy * HSZ;
            const int gy = by - 3 + hy;
            const int gx = bx - 3 + hx;
            if ((unsigned)gy < (unsigned)H && (unsigned)gx < (unsigned)W) {
                const float* sp = xb + gy * W + gx;
#pragma unroll
                for (int c = 0; c < 8; ++c) hv[it][c] = sp[c * HW];
            }
        }
    }

    // ---- load + normalize the 49 per-pixel weights (fp32 regs) ----
    float wreg[NT];
    float s = 0.f;
#pragma unroll
    for (int t = 0; t < NT; ++t) { wreg[t] = w[t * HW + p]; s += wreg[t]; }
    const float inv = 1.f / (s + EPSV);
#pragma unroll
    for (int t = 0; t < NT; ++t) wreg[t] *= inv;

    // z==0 blocks publish packed fp16 weights for step2
    if (z == 0) {
#pragma unroll
        for (int i = 0; i < NPAIR; ++i) {
            half2v h;
            h[0] = (_Float16)wreg[2 * i];
            h[1] = (2 * i + 1 < NT) ? (_Float16)wreg[2 * i + 1] : (_Float16)0.f;
            nwh[i * HW + p] = h;
        }
    }

    // ---- convert + stage halo to LDS ----
#pragma unroll
    for (int it = 0; it < 2; ++it) {
        const int i = hidx[it];
        if (i < HSZ * HSZ) {
            const int hy = i / HSZ;
            const int hx = i - hy * HSZ;
            half8 h;
#pragma unroll
            for (int c = 0; c < 8; ++c) h[c] = (_Float16)hv[it][c];
            xs[hy][hx] = h;
        }
    }
    __syncthreads();

    float acc[8];
#pragma unroll
    for (int k = 0; k < 8; ++k) acc[k] = 0.f;

#pragma unroll
    for (int i = 0; i < 7; ++i) {
#pragma unroll
        for (int j = 0; j < 7; ++j) {
            const float wf = wreg[i * 7 + j];
            const half8 v = xs[ty + i][tx + j];
#pragma unroll
            for (int k = 0; k < 8; ++k)
                acc[k] = fmaf(wf, (float)v[k], acc[k]);
        }
    }

    half8 h;
#pragma unroll
    for (int k = 0; k < 8; ++k) h[k] = (_Float16)acc[k];
    *(half8*)(x1h + ((size_t)z * HW + p) * 8) = h;
}

// ---- step2: lean (packed weights + packed staging) + partial 1x1 conv ------
__global__ __launch_bounds__(256) void step2_kernel(const _Float16* __restrict__ xin,
                                                    const half2v* __restrict__ nwh,
                                                    const float* __restrict__ cw,
                                                    float* __restrict__ partial) {
    __shared__ half8 xs[HSZ][HSZ];
    const int tx = threadIdx.x & 15;
    const int ty = threadIdx.x >> 4;
    const int bx = blockIdx.x * TS;
    const int by = blockIdx.y * TS;
    const int px = bx + tx;
    const int py = by + ty;
    const int p = py * W + px;
    const int z = blockIdx.z;

    // stage halo (issue loads first)
    const _Float16* __restrict__ xz = xin + (size_t)z * HW * 8;
    half8 hv[2];
    int hidx[2];
#pragma unroll
    for (int it = 0; it < 2; ++it) {
        const int i = threadIdx.x + it * 256;
        hidx[it] = i;
#pragma unroll
        for (int c = 0; c < 8; ++c) hv[it][c] = (_Float16)0.f;
        if (i < HSZ * HSZ) {
            const int hy = i / HSZ;
            const int hx = i - hy * HSZ;
            const int gy = by - 3 + hy;
            const int gx = bx - 3 + hx;
            if ((unsigned)gy < (unsigned)H && (unsigned)gx < (unsigned)W)
                hv[it] = *(const half8*)(xz + (size_t)(gy * W + gx) * 8);
        }
    }

    // 25 packed weight dwords (normalized fp16 pairs)
    half2v wu[NPAIR];
#pragma unroll
    for (int i = 0; i < NPAIR; ++i) wu[i] = nwh[i * HW + p];

#pragma unroll
    for (int it = 0; it < 2; ++it) {
        const int i = hidx[it];
        if (i < HSZ * HSZ) {
            const int hy = i / HSZ;
            const int hx = i - hy * HSZ;
            xs[hy][hx] = hv[it];
        }
    }
    __syncthreads();

    float acc[8];
#pragma unroll
    for (int k = 0; k < 8; ++k) acc[k] = 0.f;

#pragma unroll
    for (int i = 0; i < 7; ++i) {
#pragma unroll
        for (int j = 0; j < 7; ++j) {
            const int t = i * 7 + j;
            const float wf = (float)wu[t >> 1][t & 1];
            const half8 v = xs[ty + i][tx + j];
#pragma unroll
            for (int k = 0; k < 8; ++k)
                acc[k] = fmaf(wf, (float)v[k], acc[k]);
        }
    }

    float o0 = 0.f, o1 = 0.f, o2 = 0.f;
    const int cbase = z * CC;
#pragma unroll
    for (int k = 0; k < 8; ++k) {
        const int c = cbase + k;
        o0 = fmaf(acc[k], cw[c], o0);
        o1 = fmaf(acc[k], cw[NC + c], o1);
        o2 = fmaf(acc[k], cw[2 * NC + c], o2);
    }
    partial[(z * 3 + 0) * HW + p] = o0;
    partial[(z * 3 + 1) * HW + p] = o1;
    partial[(z * 3 + 2) * HW + p] = o2;
}

// ---- fused z-reduce + bias + bilinear x4 upsample --------------------------
#define OUTS 384
#define SRCP 10
__global__ __launch_bounds__(256) void upsample_kernel(const float* __restrict__ partial,
                                                       const float* __restrict__ cb,
                                                       float* __restrict__ dst) {
    __shared__ float cvs[3][SRCP][SRCP];
    const int X = blockIdx.x * 32;
    const int Y = blockIdx.y * 32;
    const int x0s = X >> 2;
    const int y0s = Y >> 2;

    for (int e = threadIdx.x; e < 3 * SRCP * SRCP; e += 256) {
        int ch = e / (SRCP * SRCP);
        int r = e - ch * (SRCP * SRCP);
        int sy = r / SRCP;
        int sx = r - sy * SRCP;
        int gy = min(max(y0s - 1 + sy, 0), H - 1);
        int gx = min(max(x0s - 1 + sx, 0), W - 1);
        const int p = gy * W + gx;
        float sum = cb[ch];
#pragma unroll
        for (int z = 0; z < NZ; ++z) sum += partial[(z * 3 + ch) * HW + p];
        cvs[ch][sy][sx] = sum;
    }
    __syncthreads();

    const int xl = threadIdx.x & 31;
    const int yl0 = threadIdx.x >> 5;
    const int xo = X + xl;
    const float sxf = xo * 0.25f - 0.375f;
    const float fxf = floorf(sxf);
    const int jx = (int)fxf - (x0s - 1);
    const float fx = sxf - fxf;

#pragma unroll
    for (int k = 0; k < 4; ++k) {
        const int yo = Y + yl0 + 8 * k;
        const float syf = yo * 0.25f - 0.375f;
        const float fyf = floorf(syf);
        const int jy = (int)fyf - (y0s - 1);
        const float fy = syf - fyf;
#pragma unroll
        for (int ch = 0; ch < 3; ++ch) {
            const float v00 = cvs[ch][jy][jx], v01 = cvs[ch][jy][jx + 1];
            const float v10 = cvs[ch][jy + 1][jx], v11 = cvs[ch][jy + 1][jx + 1];
            const float v0 = v00 + (v01 - v00) * fx;
            const float v1 = v10 + (v11 - v10) * fx;
            dst[ch * OUTS * OUTS + yo * OUTS + xo] = v0 + (v1 - v0) * fy;
        }
    }
}

extern "C" void kernel_launch(void* const* d_in, const int* in_sizes, int n_in,
                              void* d_out, int out_size, void* d_ws, size_t ws_size,
                              hipStream_t stream) {
    const float* input  = (const float*)d_in[0];   // (1,256,96,96)
    const float* weight = (const float*)d_in[1];   // (1,49,9216)
    const float* conv_w = (const float*)d_in[2];   // (3,256)
    const float* conv_b = (const float*)d_in[3];   // (3,)
    float* out = (float*)d_out;                    // (1,3,384,384)

    char* ws = (char*)d_ws;
    _Float16* x1h   = (_Float16*)ws;                         // 32*9216*8*2 = 4.72 MB
    half2v*   nwh   = (half2v*)(x1h + (size_t)NZ * HW * 8);  // 25*9216*4 = 0.92 MB
    float*  partial = (float*)((char*)nwh + (size_t)NPAIR * HW * 4);  // 32*3*9216*4

    dim3 g(W / TS, H / TS, NZ);               // (6,6,32)
    step1_kernel<<<g, 256, 0, stream>>>(input, weight, x1h, nwh);
    step2_kernel<<<g, 256, 0, stream>>>(x1h, nwh, conv_w, partial);

    dim3 gu(OUTS / 32, OUTS / 32);            // (12,12)
    upsample_kernel<<<gu, 256, 0, stream>>>(partial, conv_b, out);
}